// Round 2
// baseline (684.243 us; speedup 1.0000x reference)
//
#include <hip/hip_runtime.h>
#include <stdint.h>

typedef uint16_t u16;
typedef uint32_t u32;
typedef __attribute__((ext_vector_type(4))) int   int4v;    // 16B
typedef __attribute__((ext_vector_type(4))) short short4v;  // 8B
typedef __attribute__((ext_vector_type(8))) short short8;   // bf16x8 MFMA frag
typedef __attribute__((ext_vector_type(4))) float float4v;  // 16B / MFMA acc

// ---- helpers ----
__device__ __forceinline__ u16 f2bf(float f) {   // fp32 -> bf16 RNE
  u32 x = __float_as_uint(f);
  x += 0x7fffu + ((x >> 16) & 1u);
  return (u16)(x >> 16);
}
__device__ __forceinline__ void llds16(const u16* g, u16* l) {
  // async global->LDS, 16B/lane; LDS dest = wave-uniform base + lane*16
  __builtin_amdgcn_global_load_lds(
      (const __attribute__((address_space(1))) void*)g,
      (__attribute__((address_space(3))) void*)l, 16, 0, 0);
}

// B=128, T=2048, J=128, D=512  (fp32 inputs per reference)
#define BB 128
#define TT 2048
#define JJ 128
#define DD 512

// ---------------------------------------------------------------------------
// Kernel 1: U fp32 [B][J=128][D=512] -> Ut bf16 [B][D=512][J=128]
// Block = (b, 64-wide d-slab). LDS tile bf16 [128 j][72 pad].
// ---------------------------------------------------------------------------
__global__ __launch_bounds__(256) void u_transpose(const float* __restrict__ U,
                                                   u16* __restrict__ Ut) {
  __shared__ u16 tile[128 * 72];
  const int t  = threadIdx.x;
  const int b  = blockIdx.x >> 3;
  const int d0 = (blockIdx.x & 7) << 6;
  const float* src = U + (size_t)b * (JJ * DD);
  u16* dst         = Ut + (size_t)b * (DD * JJ);
#pragma unroll
  for (int i = 0; i < 8; ++i) {            // 128 rows * 16 float4 = 2048 chunks
    int idx = i * 256 + t;
    int j = idx >> 4, c = idx & 15;        // c: float4 chunk in 64-wide slab
    float4v v = *(const float4v*)(src + (size_t)j * DD + d0 + c * 4);
    short4v p;
#pragma unroll
    for (int e = 0; e < 4; ++e) p[e] = (short)f2bf(v[e]);
    *(short4v*)(tile + j * 72 + c * 4) = p; // row stride 144B; 8B aligned
  }
  __syncthreads();
#pragma unroll
  for (int i = 0; i < 4; ++i) {            // 64 d-rows * 16 j-chunks = 1024
    int idx = i * 256 + t;
    int n = idx >> 4, cj = idx & 15;
    short8 vv;
#pragma unroll
    for (int k = 0; k < 8; ++k) vv[k] = (short)tile[(cj * 8 + k) * 72 + n];
    *(short8*)(dst + (size_t)(d0 + n) * JJ + cj * 8) = vv;
  }
}

// ---------------------------------------------------------------------------
// Kernel 2: fused softmax (fp32) + bf16 MFMA GEMM, fp32 out.
// Block = (b, tm, tn) -> 128 t-rows x 128 d-cols. 256 thr = 4 waves (2x2 of 64x64).
// LDS: a_lds/b_lds = 4 K-slabs [128][32] bf16 each (32 KiB each);
//      epilogue reuses the whole buffer as fp32 out tile [128][132].
// ---------------------------------------------------------------------------
__global__ __launch_bounds__(256, 2) void softmax_gemm(const float* __restrict__ S,
                                                       const u16* __restrict__ Ut,
                                                       float* __restrict__ O) {
  __shared__ __align__(16) char smem[128 * 132 * 4];   // 67584 B
  u16* a_lds   = (u16*)smem;             // 32 KiB
  u16* b_lds   = (u16*)(smem + 32768);   // 32 KiB
  float* o_lds = (float*)smem;           // 66 KiB (epilogue reuse)

  const int tid = threadIdx.x;
  const int bi  = blockIdx.x;
  const int tn  = bi & 3;
  const int tm  = (bi >> 2) & 15;
  const int b   = bi >> 6;
  const int wave = tid >> 6;
  const int lane = tid & 63;

  // ---- async B staging first (in flight under softmax) ----
  // b_lds[s*4096 + n*32 + kk] = Ut[b][tn*128+n][s*32+kk]
  {
    const u16* utb = Ut + ((size_t)b * DD + tn * 128) * JJ;
#pragma unroll
    for (int i = 0; i < 8; ++i) {          // 2048 chunks * 16B = 32 KiB
      int ch = i * 256 + tid;
      int s = ch >> 9, n = (ch >> 2) & 127, c4 = ch & 3;
      const u16* g = utb + n * JJ + s * 32 + c4 * 8;
      u16* l = b_lds + (size_t)(i * 256 + wave * 64) * 8;  // wave-uniform base
      llds16(g, l);
    }
  }

  // ---- softmax: 2 threads per row, 64 fp32 each ----
  const int m = tid >> 1, h = tid & 1;
  const float* srow = S + ((size_t)b * TT + tm * 128 + m) * JJ + h * 64;
  float x[64];
#pragma unroll
  for (int c = 0; c < 16; ++c) {
    float4v v = ((const float4v*)srow)[c];
#pragma unroll
    for (int e = 0; e < 4; ++e) x[c * 4 + e] = v[e];
  }
  float mx = -1e30f;
#pragma unroll
  for (int e = 0; e < 64; ++e) mx = fmaxf(mx, x[e]);
  mx = fmaxf(mx, __shfl_xor(mx, 1, 64));
  float sum = 0.f;
#pragma unroll
  for (int e = 0; e < 64; ++e) { x[e] = __expf(x[e] - mx); sum += x[e]; }
  sum += __shfl_xor(sum, 1, 64);
  const float rs = 1.0f / sum;
  // write normalized bf16 into swizzled slab layout:
  // elem (m,k): s=k>>5, q=(k>>3)&3, phys chunk = q ^ ((m>>1)&3)
#pragma unroll
  for (int c = 0; c < 8; ++c) {
    short8 us;
#pragma unroll
    for (int e = 0; e < 8; ++e) us[e] = (short)f2bf(x[c * 8 + e] * rs);
    int s  = h * 2 + (c >> 2);
    int qp = (c & 3) ^ ((m >> 1) & 3);
    *(short8*)(a_lds + s * 4096 + m * 32 + qp * 8) = us;
  }

  __syncthreads();   // drains global_load_lds (vmcnt) + ds_writes

  // ---- MFMA: wave (wm,wn) owns 64x64; 4x4 tiles of 16x16x32 ----
  const int wm = wave & 1, wn = wave >> 1;
  const int ml = lane & 15, quad = lane >> 4;

  float4v acc[4][4];
#pragma unroll
  for (int mi = 0; mi < 4; ++mi)
#pragma unroll
    for (int ni = 0; ni < 4; ++ni) {
      float4v z = {0.f, 0.f, 0.f, 0.f};
      acc[mi][ni] = z;
    }

#pragma unroll
  for (int s = 0; s < 4; ++s) {
    short8 av[4], bv[4];
#pragma unroll
    for (int mi = 0; mi < 4; ++mi) {
      int mm = wm * 64 + mi * 16 + ml;
      int qp = quad ^ ((mm >> 1) & 3);
      av[mi] = *(const short8*)(a_lds + s * 4096 + mm * 32 + qp * 8);
    }
#pragma unroll
    for (int ni = 0; ni < 4; ++ni) {
      int nn = wn * 64 + ni * 16 + ml;
      bv[ni] = *(const short8*)(b_lds + s * 4096 + nn * 32 + quad * 8);
    }
#pragma unroll
    for (int mi = 0; mi < 4; ++mi)
#pragma unroll
      for (int ni = 0; ni < 4; ++ni)
        acc[mi][ni] = __builtin_amdgcn_mfma_f32_16x16x32_bf16(av[mi], bv[ni],
                                                              acc[mi][ni], 0, 0, 0);
  }

  __syncthreads();   // all frag reads done; smem reusable as fp32 out tile

  // ---- epilogue: acc -> o_lds [128][132] fp32 (pad kills worst conflicts) ----
  // C/D layout: col = lane&15, row = quad*4 + reg (m89-verified)
#pragma unroll
  for (int mi = 0; mi < 4; ++mi) {
    int row0 = wm * 64 + mi * 16 + quad * 4;
#pragma unroll
    for (int ni = 0; ni < 4; ++ni) {
      int col = wn * 64 + ni * 16 + ml;
#pragma unroll
      for (int rr = 0; rr < 4; ++rr)
        o_lds[(row0 + rr) * 132 + col] = acc[mi][ni][rr];
    }
  }
  __syncthreads();

  // ---- coalesced 16B fp32 global stores ----
  float* ob = O + ((size_t)b * TT + tm * 128) * DD + tn * 128;
#pragma unroll
  for (int i = 0; i < 16; ++i) {
    int ch = i * 256 + tid;                // 4096 float4 chunks
    int row = ch >> 5, c = ch & 31;
    *(float4v*)(ob + (size_t)row * DD + c * 4) =
        *(const float4v*)(o_lds + row * 132 + c * 4);
  }
}

// ---------------------------------------------------------------------------
extern "C" void kernel_launch(void* const* d_in, const int* in_sizes, int n_in,
                              void* d_out, int out_size, void* d_ws, size_t ws_size,
                              hipStream_t stream) {
  (void)in_sizes; (void)n_in; (void)out_size; (void)ws_size;
  const float* U = (const float*)d_in[0];  // [128][128][512] fp32
  const float* S = (const float*)d_in[1];  // [128][2048][128] fp32
  float* out = (float*)d_out;              // [128][2048][512] fp32
  u16* Ut    = (u16*)d_ws;                 // [128][512][128] bf16 = 8 MiB scratch

  u_transpose<<<BB * 8, 256, 0, stream>>>(U, Ut);
  softmax_gemm<<<BB * 16 * 4, 256, 0, stream>>>(S, Ut, out);
}